// Round 7
// baseline (254.639 us; speedup 1.0000x reference)
//
#include <hip/hip_runtime.h>

// Sort_Latent_Layer: per row of (4096, 8192) fp32, view as 512 packets of 16,
// stable-argsort packets by first element, emit packets in sorted order.
//
// v5: one wave per row, zero barriers in the whole kernel.
//  - 64 lanes x 8 elements/lane register-resident bitonic over virtual index
//    e = lane*8 + s (lane-major). 24/45 steps are in-register VALU only;
//    21/45 cross-lane steps shuffle 8 u64: lane-dist 1,2 via DPP quad_perm
//    (VALU pipe), 4/8/16 via ds_swizzle, 32 via __shfl_xor.
//    LDS-pipe ops ~650 -> ~160 per row; barriers 12 -> 0.
//  - 256-thread blocks = 4 independent waves = 4 rows; 8 blocks/CU = 32
//    decoupled wave-pipelines per CU (v4 had 4 barrier-lockstep pipelines).
//  - Keys packed (monotonic(f32)<<16 | e): stable, tie-exact.
//  - Gather straight from global (L2/L3-hot from the key-load pass),
//    per-wave srcs[] in LDS (wave-internal dep only), coalesced nt stores.

#define NPK 512       // packets per row
#define DIM 8192      // floats per row
#define NT  256       // threads per block = 4 waves = 4 rows
#define RPB 4         // rows per block

typedef float vfloat4 __attribute__((ext_vector_type(4)));

// xor-shuffle of 32 bits by lane-distance lj (callers pass foldable constants;
// each branch has literal immediates as the builtins require)
__device__ __forceinline__ unsigned int sx32(unsigned int x, int lj) {
    if (lj == 1)  return (unsigned int)__builtin_amdgcn_mov_dpp((int)x, 0xB1, 0xF, 0xF, true); // quad_perm [1,0,3,2]
    if (lj == 2)  return (unsigned int)__builtin_amdgcn_mov_dpp((int)x, 0x4E, 0xF, 0xF, true); // quad_perm [2,3,0,1]
    if (lj == 4)  return (unsigned int)__builtin_amdgcn_ds_swizzle((int)x, 0x101F);
    if (lj == 8)  return (unsigned int)__builtin_amdgcn_ds_swizzle((int)x, 0x201F);
    if (lj == 16) return (unsigned int)__builtin_amdgcn_ds_swizzle((int)x, 0x401F);
    return (unsigned int)__shfl_xor((int)x, lj);   // lj == 32
}

__device__ __forceinline__ unsigned long long sx64(unsigned long long v, int lj) {
    const unsigned int lo = sx32((unsigned int)v, lj);
    const unsigned int hi = sx32((unsigned int)(v >> 32), lj);
    return ((unsigned long long)hi << 32) | lo;
}

__global__ __launch_bounds__(NT, 8)
void sort_latent_kernel(const float* __restrict__ z, float* __restrict__ out) {
    __shared__ int srcs[RPB][NPK];                 // 8 KB, per-wave regions

    const int t    = threadIdx.x;
    const int w    = t >> 6;                       // wave id = row within block
    const int lane = t & 63;
    const size_t rowoff = ((size_t)blockIdx.x * RPB + w) * DIM;
    const float*  __restrict__ zrow = z + rowoff;
    const vfloat4* __restrict__ zin4 = (const vfloat4*)zrow;
    vfloat4* __restrict__ out4 = (vfloat4*)(out + rowoff);

    // ---- Keys: element e = lane*8+s reads packet e's first float.
    // Touches every 64B line of the row => warms L2/L3 for the gather.
    unsigned long long v[8];
#pragma unroll
    for (int s = 0; s < 8; ++s) {
        const int e = lane * 8 + s;
        unsigned int u = __float_as_uint(zrow[e * 16]);
        if (u == 0x80000000u) u = 0u;              // -0.0 -> +0.0 (tie w/ +0.0)
        u = (u & 0x80000000u) ? ~u : (u | 0x80000000u);  // monotonic map
        v[s] = ((unsigned long long)u << 16) | (unsigned long long)e;
    }

    // ---- Bitonic sort of 512 over (lane, slot), fully in-wave ----
#pragma unroll
    for (int kk = 1; kk <= 9; ++kk) {
        const int k = 1 << kk;
#pragma unroll
        for (int jj = kk - 1; jj >= 0; --jj) {
            const int j = 1 << jj;
            if (j >= 8) {
                // cross-lane: partner lane = lane ^ (j>>3), same slot
                const int lj = j >> 3;
                const bool up = ((lane & (k >> 3)) == 0);      // e&k from lane (k>=16)
                const bool keep_min = (up == ((lane & lj) == 0)); // e&j from lane
#pragma unroll
                for (int s = 0; s < 8; ++s) {
                    const unsigned long long a  = v[s];
                    const unsigned long long vp = sx64(a, lj);
                    const bool lt = a < vp;                    // never equal (e unique)
                    v[s] = (keep_min == lt) ? a : vp;
                }
            } else {
                // in-thread: pairs (s, s|j) within the 8 slots
#pragma unroll
                for (int s = 0; s < 8; ++s) {
                    if ((s & j) == 0) {
                        const int p = s | j;
                        const bool up = ((((lane << 3) | s) & k) == 0); // e&k
                        const unsigned long long a = v[s], b = v[p];
                        const bool lt = a < b;
                        const bool do_swap = (lt != up);
                        v[s] = do_swap ? b : a;
                        v[p] = do_swap ? a : b;
                    }
                }
            }
        }
    }

    // ---- Scatter sorted source indices to this wave's srcs[] (wave-internal
    // RAW through LDS: compiler-inserted lgkmcnt orders it; no barrier).
#pragma unroll
    for (int s = 0; s < 8; ++s)
        srcs[w][lane * 8 + s] = (int)(v[s] & 0xffffull);

    // ---- Gather packets straight from global (cache-hot); coalesced nt stores.
#pragma unroll 8
    for (int i = 0; i < DIM / 4 / 64; ++i) {       // 32 iters
        const int o = i * 64 + lane;               // dest float4 slot in row
        const int src = srcs[w][o >> 2];           // 4-lane broadcast read
        const vfloat4 val = zin4[src * 4 + (o & 3)];
        __builtin_nontemporal_store(val, &out4[o]);
    }
}

extern "C" void kernel_launch(void* const* d_in, const int* in_sizes, int n_in,
                              void* d_out, int out_size, void* d_ws, size_t ws_size,
                              hipStream_t stream) {
    const float* z = (const float*)d_in[0];
    float* out = (float*)d_out;
    const int nrows = in_sizes[0] / DIM;           // 4096
    sort_latent_kernel<<<nrows / RPB, NT, 0, stream>>>(z, out);
}